// Round 10
// baseline (247.198 us; speedup 1.0000x reference)
//
#include <hip/hip_runtime.h>
#include <hip/hip_bf16.h>

#define N_NODES 10000
#define N_EDGES 320000
#define HIDDEN 256
#define HEADS 8
#define HEAD_DIM 32
#define NEG_SLOPE 0.2f

typedef __attribute__((ext_vector_type(8))) short short8;   // 8 bf16 (4 VGPRs)
typedef __attribute__((ext_vector_type(4))) float f32x4;

__device__ __forceinline__ void bf16_split(float v, unsigned short& hi, unsigned short& lo) {
    __hip_bfloat16 hb = __float2bfloat16(v);
    float hf = __bfloat162float(hb);
    __hip_bfloat16 lb = __float2bfloat16(v - hf);
    hi = *reinterpret_cast<unsigned short*>(&hb);
    lo = *reinterpret_cast<unsigned short*>(&lb);
}

// ---------------- fused prep: split+transpose W1,W2 + dst-histogram w/ rank ----------------
// blocks [0,512): W split; [512,1762): hist (rank[e] = arrival order within dst node).
__global__ __launch_bounds__(256) void prep_kernel(
    const float* __restrict__ W1, const float* __restrict__ W2,
    const int* __restrict__ dst,
    unsigned short* __restrict__ w1h, unsigned short* __restrict__ w1l,
    unsigned short* __restrict__ w2h, unsigned short* __restrict__ w2l,
    int* __restrict__ counts, int* __restrict__ rank) {
    int b = blockIdx.x;
    int tid = threadIdx.x;
    if (b < 512) {                         // split+transpose W: 2*65536 elems
        int i = b * 256 + tid;
        int which = i >> 16;
        int rem = i & 0xFFFF;
        int k = rem >> 8, n = rem & 255;
        const float* W = which ? W2 : W1;
        unsigned short* wh = which ? w2h : w1h;
        unsigned short* wl = which ? w2l : w1l;
        unsigned short h, l;
        bf16_split(W[k * 256 + n], h, l);
        wh[n * 256 + k] = h;
        wl[n * 256 + k] = l;
    } else {                               // histogram over dst (1250*256 == N_EDGES)
        int e = (b - 512) * 256 + tid;
        rank[e] = atomicAdd(&counts[dst[e]], 1);
    }
}

// ---------------- MFMA GEMM: C[10000,256] = A * B, split-bf16 ----------------
// C = Ah*Bh + Ah*Bl + Al*Bh (Al*Bl ~ 2^-18, dropped). Tile 80x128, 250 GEMM blocks
// = 1/CU exactly, no tail, no M-guards. 4 waves; wave w owns cols w*32..w*32+31
// (= head bx*4+w), 5 row-tiles of 16. 2-stage register prefetch pipeline.
// AFP32: stage A from fp32 with in-register bf16 split (layer 1).
// FUSE_SCATTER: blocks >= 250 perform the CSR scatter (independent work, hidden
// under the GEMM; deps prep+scan are done). Epilogue: fp32 C + fused alpha dots.
template <int AFP32, int FUSE_SCATTER>
__global__ __launch_bounds__(256) void gemm_mfma_kernel(
    const float* __restrict__ Axf,
    const unsigned short* __restrict__ Ah, const unsigned short* __restrict__ Al,
    const unsigned short* __restrict__ BhT, const unsigned short* __restrict__ BlT,
    float* __restrict__ C, const float* __restrict__ a_src,
    const float* __restrict__ a_dst, float* __restrict__ alpha_s,
    float* __restrict__ alpha_d,
    const int* __restrict__ srcE, const int* __restrict__ dstE,
    const int* __restrict__ row_ptr, const int* __restrict__ rank,
    int* __restrict__ csr_src) {
    if (FUSE_SCATTER && blockIdx.x >= 250) {
        int e = (blockIdx.x - 250) * 256 + threadIdx.x;
        if (e < N_EDGES) csr_src[row_ptr[dstE[e]] + rank[e]] = srcE[e];
        return;
    }
    // pitch 40 ushorts (80 B): ds_read_b128 pattern is 2-way (free)
    __shared__ __align__(16) unsigned short sAh[80 * 40];
    __shared__ __align__(16) unsigned short sAl[80 * 40];
    __shared__ __align__(16) unsigned short sBh[128 * 40];
    __shared__ __align__(16) unsigned short sBl[128 * 40];
    const int tid = threadIdx.x;
    const int w = tid >> 6, lane = tid & 63;
    const int col = lane & 15, quad = lane >> 4;
    const int bx = blockIdx.x & 1, by = blockIdx.x >> 1;   // 250 = 2 x 125
    const int m0 = by * 80, n0 = bx * 128;

    f32x4 acc[5][2] = {};

    float4 raf[3];
    uint4 rau[3];
    uint4 rb[4];

    // A: 640 tasks (fp32: row=t>>3,seg=t&7 float4 | bf16: 320 hi + 320 lo uint4)
    // B: 1024 tasks = 512 hi + 512 lo uint4 (exactly 4*256, no guard)
#define LOAD_A(k0)                                                              \
    if (AFP32) {                                                                \
        _Pragma("unroll") for (int i = 0; i < 3; ++i) {                         \
            int t = tid + i * 256;                                              \
            if (t < 640) {                                                      \
                int row = t >> 3, seg = t & 7;                                  \
                raf[i] = *(const float4*)&Axf[(size_t)(m0 + row) * 256 + (k0) + seg * 4]; \
            }                                                                   \
        }                                                                       \
    } else {                                                                    \
        _Pragma("unroll") for (int i = 0; i < 3; ++i) {                         \
            int t = tid + i * 256;                                              \
            if (t < 640) {                                                      \
                int tt = t < 320 ? t : t - 320;                                 \
                int row = tt >> 2, seg = tt & 3;                                \
                const unsigned short* P = t < 320 ? Ah : Al;                    \
                rau[i] = *(const uint4*)&P[(size_t)(m0 + row) * 256 + (k0) + seg * 8]; \
            }                                                                   \
        }                                                                       \
    }
#define LOAD_B(k0)                                                              \
    _Pragma("unroll") for (int i = 0; i < 4; ++i) {                             \
        int t = tid + i * 256;                                                  \
        int tt = t < 512 ? t : t - 512;                                         \
        int row = tt >> 2, seg = tt & 3;                                        \
        const unsigned short* P = t < 512 ? BhT : BlT;                          \
        rb[i] = *(const uint4*)&P[(size_t)(n0 + row) * 256 + (k0) + seg * 8];   \
    }

    LOAD_A(0)
    LOAD_B(0)

    for (int ks = 0; ks < 8; ++ks) {
        // ---- write staged registers to LDS ----
        if (AFP32) {
#pragma unroll
            for (int i = 0; i < 3; ++i) {
                int t = tid + i * 256;
                if (t < 640) {
                    int row = t >> 3, seg = t & 7;
                    float4 v = raf[i];
                    ushort4 hh, ll;
                    unsigned short hb, lb;
                    bf16_split(v.x, hb, lb); hh.x = hb; ll.x = lb;
                    bf16_split(v.y, hb, lb); hh.y = hb; ll.y = lb;
                    bf16_split(v.z, hb, lb); hh.z = hb; ll.z = lb;
                    bf16_split(v.w, hb, lb); hh.w = hb; ll.w = lb;
                    *(ushort4*)&sAh[row * 40 + seg * 4] = hh;
                    *(ushort4*)&sAl[row * 40 + seg * 4] = ll;
                }
            }
        } else {
#pragma unroll
            for (int i = 0; i < 3; ++i) {
                int t = tid + i * 256;
                if (t < 640) {
                    int tt = t < 320 ? t : t - 320;
                    int row = tt >> 2, seg = tt & 3;
                    unsigned short* S = t < 320 ? sAh : sAl;
                    *(uint4*)&S[row * 40 + seg * 8] = rau[i];
                }
            }
        }
#pragma unroll
        for (int i = 0; i < 4; ++i) {
            int t = tid + i * 256;
            int tt = t < 512 ? t : t - 512;
            int row = tt >> 2, seg = tt & 3;
            unsigned short* S = t < 512 ? sBh : sBl;
            *(uint4*)&S[row * 40 + seg * 8] = rb[i];
        }
        __syncthreads();

        // ---- prefetch next K-step while MFMAs run ----
        if (ks < 7) {
            int nk = (ks + 1) * 32;
            LOAD_A(nk)
            LOAD_B(nk)
        }

        // ---- compute ----
        short8 bh0 = *(const short8*)&sBh[(w * 32 + col) * 40 + quad * 8];
        short8 bl0 = *(const short8*)&sBl[(w * 32 + col) * 40 + quad * 8];
        short8 bh1 = *(const short8*)&sBh[(w * 32 + 16 + col) * 40 + quad * 8];
        short8 bl1 = *(const short8*)&sBl[(w * 32 + 16 + col) * 40 + quad * 8];
#pragma unroll
        for (int rt = 0; rt < 5; ++rt) {
            short8 ah = *(const short8*)&sAh[(rt * 16 + col) * 40 + quad * 8];
            short8 al = *(const short8*)&sAl[(rt * 16 + col) * 40 + quad * 8];
            acc[rt][0] = __builtin_amdgcn_mfma_f32_16x16x32_bf16(ah, bh0, acc[rt][0], 0, 0, 0);
            acc[rt][0] = __builtin_amdgcn_mfma_f32_16x16x32_bf16(ah, bl0, acc[rt][0], 0, 0, 0);
            acc[rt][0] = __builtin_amdgcn_mfma_f32_16x16x32_bf16(al, bh0, acc[rt][0], 0, 0, 0);
            acc[rt][1] = __builtin_amdgcn_mfma_f32_16x16x32_bf16(ah, bh1, acc[rt][1], 0, 0, 0);
            acc[rt][1] = __builtin_amdgcn_mfma_f32_16x16x32_bf16(ah, bl1, acc[rt][1], 0, 0, 0);
            acc[rt][1] = __builtin_amdgcn_mfma_f32_16x16x32_bf16(al, bh1, acc[rt][1], 0, 0, 0);
        }
        __syncthreads();
    }
#undef LOAD_A
#undef LOAD_B

    // ---- epilogue: C/D layout col=lane&15, row=quad*4+reg ----
    const int head = bx * 4 + w;
    float as0 = a_src[n0 + w * 32 + col];
    float as1 = a_src[n0 + w * 32 + 16 + col];
    float ad0 = a_dst[n0 + w * 32 + col];
    float ad1 = a_dst[n0 + w * 32 + 16 + col];
#pragma unroll
    for (int rt = 0; rt < 5; ++rt) {
#pragma unroll
        for (int r = 0; r < 4; ++r) {
            int gm = m0 + rt * 16 + quad * 4 + r;
            C[(size_t)gm * 256 + n0 + w * 32 + col]      = acc[rt][0][r];
            C[(size_t)gm * 256 + n0 + w * 32 + 16 + col] = acc[rt][1][r];
            float ps = acc[rt][0][r] * as0 + acc[rt][1][r] * as1;
            float pd = acc[rt][0][r] * ad0 + acc[rt][1][r] * ad1;
#pragma unroll
            for (int m = 1; m < 16; m <<= 1) {
                ps += __shfl_xor(ps, m);
                pd += __shfl_xor(pd, m);
            }
            if (col == 0) {
                alpha_s[gm * HEADS + head] = ps;
                alpha_d[gm * HEADS + head] = pd;
            }
        }
    }
}

// ---------------- CSR scan (rank-based scatter needs no cursor) ----------------
__global__ __launch_bounds__(256) void scan_kernel(const int* __restrict__ counts,
                                                   int* __restrict__ row_ptr) {
    __shared__ int wsum[4];
    const int tid = threadIdx.x;
    const int lane = tid & 63, w = tid >> 6;
    const int CH = (N_NODES + 255) / 256;  // 40
    int base = tid * CH;
    int s = 0;
    for (int i = 0; i < CH; ++i) {
        int idx = base + i;
        if (idx < N_NODES) s += counts[idx];
    }
    int inc = s;
#pragma unroll
    for (int off = 1; off < 64; off <<= 1) {
        int v = __shfl_up(inc, off);
        if (lane >= off) inc += v;
    }
    if (lane == 63) wsum[w] = inc;
    __syncthreads();
    int woff = 0;
    for (int i = 0; i < w; ++i) woff += wsum[i];
    int run = woff + inc - s;
    for (int i = 0; i < CH; ++i) {
        int idx = base + i;
        if (idx < N_NODES) {
            row_ptr[idx] = run;
            run += counts[idx];
        }
    }
    if (tid == 255) row_ptr[N_NODES] = run;
}

// ---------------- fused softmax + aggregation: one WAVE per dst node ----------------
// node = blockIdx.x*4 + waveId; 64 lanes x float4 = full 1 KB row per edge load;
// unroll x4 (4 KB in flight per wave). No LDS, no syncthreads -> max occupancy.
// segment-max dropped (e is O(1), softmax shift-invariant). mode=1: ELU + bf16-split
// store (layer-2 GEMM input); mode=0: fp32 store.
__global__ __launch_bounds__(256) void aggregate_kernel(
    const int* __restrict__ row_ptr, const int* __restrict__ csr_src,
    const float* __restrict__ alpha_s, const float* __restrict__ alpha_d,
    const float* __restrict__ h, const float* __restrict__ bias,
    float* __restrict__ outf, unsigned short* __restrict__ oh,
    unsigned short* __restrict__ ol, int mode) {
    int tid = threadIdx.x;
    int lane = tid & 63;
    int d = __builtin_amdgcn_readfirstlane(blockIdx.x * 4 + (tid >> 6));
    int hd = lane >> 3;
    float ad = alpha_d[d * HEADS + hd];
    int beg = __builtin_amdgcn_readfirstlane(row_ptr[d]);
    int end = __builtin_amdgcn_readfirstlane(row_ptr[d + 1]);

    float4 acc = make_float4(0.f, 0.f, 0.f, 0.f);
    float den = 0.f;

    int slot = beg;
    for (; slot + 3 < end; slot += 4) {
        int s0 = csr_src[slot];
        int s1 = csr_src[slot + 1];
        int s2 = csr_src[slot + 2];
        int s3 = csr_src[slot + 3];
        float al0 = alpha_s[s0 * HEADS + hd];
        float al1 = alpha_s[s1 * HEADS + hd];
        float al2 = alpha_s[s2 * HEADS + hd];
        float al3 = alpha_s[s3 * HEADS + hd];
        float4 h0 = *(const float4*)&h[(size_t)s0 * HIDDEN + lane * 4];
        float4 h1 = *(const float4*)&h[(size_t)s1 * HIDDEN + lane * 4];
        float4 h2 = *(const float4*)&h[(size_t)s2 * HIDDEN + lane * 4];
        float4 h3 = *(const float4*)&h[(size_t)s3 * HIDDEN + lane * 4];
        float e0 = al0 + ad; e0 = e0 > 0.f ? e0 : NEG_SLOPE * e0;
        float e1 = al1 + ad; e1 = e1 > 0.f ? e1 : NEG_SLOPE * e1;
        float e2 = al2 + ad; e2 = e2 > 0.f ? e2 : NEG_SLOPE * e2;
        float e3 = al3 + ad; e3 = e3 > 0.f ? e3 : NEG_SLOPE * e3;
        float ev0 = __expf(e0), ev1 = __expf(e1);
        float ev2 = __expf(e2), ev3 = __expf(e3);
        den += (ev0 + ev1) + (ev2 + ev3);
        acc.x += h0.x * ev0 + h1.x * ev1 + h2.x * ev2 + h3.x * ev3;
        acc.y += h0.y * ev0 + h1.y * ev1 + h2.y * ev2 + h3.y * ev3;
        acc.z += h0.z * ev0 + h1.z * ev1 + h2.z * ev2 + h3.z * ev3;
        acc.w += h0.w * ev0 + h1.w * ev1 + h2.w * ev2 + h3.w * ev3;
    }
    for (; slot < end; ++slot) {
        int s0 = csr_src[slot];
        float al0 = alpha_s[s0 * HEADS + hd];
        float4 h0 = *(const float4*)&h[(size_t)s0 * HIDDEN + lane * 4];
        float e0 = al0 + ad; e0 = e0 > 0.f ? e0 : NEG_SLOPE * e0;
        float ev0 = __expf(e0);
        den += ev0;
        acc.x += h0.x * ev0; acc.y += h0.y * ev0;
        acc.z += h0.z * ev0; acc.w += h0.w * ev0;
    }

    float inv = 1.f / (den + 1e-16f);
    float4 bv = *(const float4*)&bias[lane * 4];
    float v[4];
    v[0] = acc.x * inv + bv.x;
    v[1] = acc.y * inv + bv.y;
    v[2] = acc.z * inv + bv.z;
    v[3] = acc.w * inv + bv.w;
    if (mode == 1) {
        ushort4 hh, ll;
        unsigned short hb, lb;
#pragma unroll
        for (int i = 0; i < 4; ++i)
            v[i] = v[i] > 0.f ? v[i] : (__expf(v[i]) - 1.f);
        bf16_split(v[0], hb, lb); hh.x = hb; ll.x = lb;
        bf16_split(v[1], hb, lb); hh.y = hb; ll.y = lb;
        bf16_split(v[2], hb, lb); hh.z = hb; ll.z = lb;
        bf16_split(v[3], hb, lb); hh.w = hb; ll.w = lb;
        *(ushort4*)&oh[(size_t)d * HIDDEN + lane * 4] = hh;
        *(ushort4*)&ol[(size_t)d * HIDDEN + lane * 4] = ll;
    } else {
        *(float4*)&outf[(size_t)d * HIDDEN + lane * 4] =
            make_float4(v[0], v[1], v[2], v[3]);
    }
}

extern "C" void kernel_launch(void* const* d_in, const int* in_sizes, int n_in,
                              void* d_out, int out_size, void* d_ws, size_t ws_size,
                              hipStream_t stream) {
    const float* x      = (const float*)d_in[0];
    const int*   edges  = (const int*)d_in[1];
    const float* W1     = (const float*)d_in[2];
    const float* as1    = (const float*)d_in[3];
    const float* ad1    = (const float*)d_in[4];
    const float* b1     = (const float*)d_in[5];
    const float* W2     = (const float*)d_in[6];
    const float* as2    = (const float*)d_in[7];
    const float* ad2    = (const float*)d_in[8];
    const float* b2     = (const float*)d_in[9];
    float* out = (float*)d_out;

    const int* src = edges;
    const int* dst = edges + N_EDGES;

    const size_t NF = (size_t)N_NODES * HIDDEN;   // 2.56M
    const size_t NH = (size_t)N_NODES * HEADS;    // 80k

    char* base = (char*)d_ws;
    float* h_buf = (float*)base;                base += NF * 4;
    unsigned short* x2h = (unsigned short*)base; base += NF * 2;
    unsigned short* x2l = (unsigned short*)base; base += NF * 2;
    float* alpha_s = (float*)base;              base += NH * 4;
    float* alpha_d = (float*)base;              base += NH * 4;
    unsigned short* w1h = (unsigned short*)base; base += 65536 * 2;
    unsigned short* w1l = (unsigned short*)base; base += 65536 * 2;
    unsigned short* w2h = (unsigned short*)base; base += 65536 * 2;
    unsigned short* w2l = (unsigned short*)base; base += 65536 * 2;
    int* csr_src = (int*)base;                  base += (size_t)N_EDGES * 4;
    int* rank    = (int*)base;                  base += (size_t)N_EDGES * 4;
    int* counts  = (int*)base;                  base += (size_t)N_NODES * 4;
    int* row_ptr = (int*)base;                  base += (size_t)(N_NODES + 1) * 4;

    const int EB = (N_EDGES + 255) / 256;   // 1250

    // ---- prep: zero counts, then fused W-split + hist(rank), then scan ----
    hipMemsetAsync(counts, 0, N_NODES * sizeof(int), stream);
    prep_kernel<<<512 + EB, 256, 0, stream>>>(W1, W2, dst, w1h, w1l, w2h, w2l,
                                              counts, rank);
    scan_kernel<<<1, 256, 0, stream>>>(counts, row_ptr);

    // ================= layer 1 (A = fp32 x; scatter fused into this dispatch) ====
    gemm_mfma_kernel<1, 1><<<250 + EB, 256, 0, stream>>>(
        x, nullptr, nullptr, w1h, w1l, h_buf, as1, ad1, alpha_s, alpha_d,
        src, dst, row_ptr, rank, csr_src);
    aggregate_kernel<<<N_NODES / 4, 256, 0, stream>>>(row_ptr, csr_src, alpha_s, alpha_d,
                                                      h_buf, b1, nullptr, x2h, x2l, 1);

    // ================= layer 2 (A = bf16 hi/lo from aggregate) =================
    gemm_mfma_kernel<0, 0><<<250, 256, 0, stream>>>(
        nullptr, x2h, x2l, w2h, w2l, h_buf, as2, ad2, alpha_s, alpha_d,
        nullptr, nullptr, nullptr, nullptr, nullptr);
    aggregate_kernel<<<N_NODES / 4, 256, 0, stream>>>(row_ptr, csr_src, alpha_s, alpha_d,
                                                      h_buf, b2, out, nullptr, nullptr, 0);
}